// Round 7
// baseline (94.251 us; speedup 1.0000x reference)
//
#include <hip/hip_runtime.h>
#include <hip/hip_bf16.h>
#include <stdint.h>

// ---- types -----------------------------------------------------------------
typedef __bf16 bf16x8 __attribute__((ext_vector_type(8)));
typedef float  f32x4  __attribute__((ext_vector_type(4)));

#define B_ROWS 8192
#define C_CLS  1000
#define P_DIM  512
#define EPS    1e-10f

__device__ __forceinline__ float dot8(float4 a, float4 b) {
    return a.x * a.x + a.y * a.y + a.z * a.z + a.w * a.w
         + b.x * b.x + b.y * b.y + b.z * b.z + b.w * b.w;
}

// ---- single fused kernel ----------------------------------------------------
// R7 = R6 resubmitted (R6 bench died to a container/broker failure, not a
// kernel verdict; source re-audited -- no OOB, no graph-capture violation,
// no LDS race, swizzle round-trip verified, VGPR ~115 under the (512,4) cap).
//
// Design: normalization commutes with the GEMM (diag(s)·X·M^T = diag(s)·(X·M^T)),
// so the MFMA runs on raw bf16(x) and the per-row scale is applied in the
// EPILOGUE. This deletes prep_k, the 17 MB xn round-trip, and one dispatch.
//   - 128x128 tile, 8 waves (R5 geometry: 2 blocks/CU x 8 waves = 16 waves/CU)
//   - K-loop stages f32 x and f32 means -> cvt bf16 -> swizzled ds_write_b128
//     (R2's proven staging addressing; ds_write may swizzle directly).
//   - row sumsq (x) and col sumsq (means) accumulate FREE from the f32 staging
//     values, per-thread across K-steps; quad-shfl reduce once after the loop.
//   - scale = ||means[0]||: wave 0, 2 KB L2-hot read, prologue.
//   - T14 prefetch: next K-step's 8 global_load_dwordx4 issue AFTER barrier 1
//     so their vmcnt drain lands at barrier 2 (window = whole MFMA phase).
//   - XCD remap (T1): per-XCD set = 2 MB f32 A-slice + 2 MB f32 B, L2-resident.
// Epilogue: out = 2*s_r*cross - xsq_r - msq_c,  s_r = scale/(norm_r+EPS),
//           xsq_r = (s_r*norm_r)^2  (exactly the reference's ||xn||^2).
// Numerics vs R1: bf16(x)*s_r instead of bf16(x*s_r) -- same rounding scale
// (s_r ~= 1 since ||x_r|| ~= ||means[0]|| ~= sqrt(512)); passed absmax=8 before.
__global__ __launch_bounds__(512, 4) void fused_k(const float* __restrict__ X,    // [8192][512] f32
                                                  const float* __restrict__ M,    // [1000][512] f32
                                                  float* __restrict__ out) {     // [8192][1000] f32
    __shared__ alignas(16) char lds[32768];      // A[128][128B] @0, B[128][128B] @16384
    __shared__ float ssq_lds[128];               // per-A-row sumsq (raw x)
    __shared__ float msq_lds[128];               // per-B-row sumsq (means)
    __shared__ float scale_lds;                  // ||means[0]||

    const int t   = threadIdx.x;
    const int w   = t >> 6;         // wave 0..7
    const int l   = t & 63;
    const int q   = l >> 4;         // quad 0..3
    const int m16 = l & 15;
    const int wr  = w >> 2;         // wave row 0..1 (64-row halves)
    const int wc  = w & 3;          // wave col 0..3 (32-col quarters)

    // XCD-aware remap: n%8 = XCD; each XCD owns 8 consecutive brows x all bcols.
    const int n_blk  = blockIdx.x;            // 0..511
    const int xcd    = n_blk & 7;
    const int within = n_blk >> 3;            // 0..63
    const int brow   = xcd * 8 + (within & 7);     // 0..63 (128-row tiles)
    const int bcol   = within >> 3;                // 0..7  (128-col tiles)

    // staging map: 4 threads per row, 16 consecutive f32 each
    const int prow = t >> 2;        // 0..127
    const int pseg = t & 3;         // 0..3

    // ---- prologue: wave 0 computes scale = ||means[0]|| (2 KB, L2-hot)
    if (w == 0) {
        const float4* m0 = (const float4*)M;
        float4 ma = m0[l * 2];
        float4 mb = m0[l * 2 + 1];
        float ms = dot8(ma, mb);
        #pragma unroll
        for (int off = 32; off > 0; off >>= 1) ms += __shfl_down(ms, off);
        if (l == 0) scale_lds = sqrtf(ms);
        // visible to all by the K-loop's first __syncthreads (read only in epilogue)
    }

    f32x4 acc[4][2];
    #pragma unroll
    for (int i = 0; i < 4; ++i)
        #pragma unroll
        for (int j = 0; j < 2; ++j) {
            f32x4 z = {0.f, 0.f, 0.f, 0.f};
            acc[i][j] = z;
        }

    const float* Arow = X + (size_t)(brow * 128 + prow) * P_DIM + pseg * 16;
    const int    grow = bcol * 128 + prow;              // global class row
    const float* Brow = M + (size_t)grow * P_DIM + pseg * 16;
    const bool   bvalid = (grow < C_CLS);

    // swizzled LDS staging addresses (R2-proven): thread covers logical chunks
    // pseg*2, pseg*2+1 of row prow; stored at chunk^(prow&7). Bank check:
    // 8 lanes per chunk-slot = the b128 wave minimum, conflict-free.
    const int sc0 = (((pseg * 2)     ^ (prow & 7)) << 4);
    const int sc1 = (((pseg * 2 + 1) ^ (prow & 7)) << 4);
    char* const awr = lds + prow * 128;
    char* const bwr = lds + 16384 + prow * 128;
    const int swz = (m16 & 7) << 4;                     // read-side XOR

    float ssqa = 0.f, ssqb = 0.f;

    // ---- prologue loads (k0 = 0); invalid B rows stay zero forever
    float4 A0, A1, A2, A3, B0, B1, B2, B3;
    {
        const float4* p = (const float4*)Arow;
        A0 = p[0]; A1 = p[1]; A2 = p[2]; A3 = p[3];
        float4 z = {0.f, 0.f, 0.f, 0.f};
        B0 = z; B1 = z; B2 = z; B3 = z;
        if (bvalid) {
            const float4* pb = (const float4*)Brow;
            B0 = pb[0]; B1 = pb[1]; B2 = pb[2]; B3 = pb[3];
        }
    }

    for (int kt = 0; kt < 8; ++kt) {
        // ---- accumulate stats + cvt + swizzled stage of the current regs
        ssqa += dot8(A0, A1) + dot8(A2, A3);
        ssqb += dot8(B0, B1) + dot8(B2, B3);
        {
            alignas(16) __hip_bfloat16 ta[16];
            ta[0]  = __float2bfloat16(A0.x); ta[1]  = __float2bfloat16(A0.y);
            ta[2]  = __float2bfloat16(A0.z); ta[3]  = __float2bfloat16(A0.w);
            ta[4]  = __float2bfloat16(A1.x); ta[5]  = __float2bfloat16(A1.y);
            ta[6]  = __float2bfloat16(A1.z); ta[7]  = __float2bfloat16(A1.w);
            ta[8]  = __float2bfloat16(A2.x); ta[9]  = __float2bfloat16(A2.y);
            ta[10] = __float2bfloat16(A2.z); ta[11] = __float2bfloat16(A2.w);
            ta[12] = __float2bfloat16(A3.x); ta[13] = __float2bfloat16(A3.y);
            ta[14] = __float2bfloat16(A3.z); ta[15] = __float2bfloat16(A3.w);
            *(uint4*)(awr + sc0) = ((const uint4*)ta)[0];
            *(uint4*)(awr + sc1) = ((const uint4*)ta)[1];
            alignas(16) __hip_bfloat16 tb[16];
            tb[0]  = __float2bfloat16(B0.x); tb[1]  = __float2bfloat16(B0.y);
            tb[2]  = __float2bfloat16(B0.z); tb[3]  = __float2bfloat16(B0.w);
            tb[4]  = __float2bfloat16(B1.x); tb[5]  = __float2bfloat16(B1.y);
            tb[6]  = __float2bfloat16(B1.z); tb[7]  = __float2bfloat16(B1.w);
            tb[8]  = __float2bfloat16(B2.x); tb[9]  = __float2bfloat16(B2.y);
            tb[10] = __float2bfloat16(B2.z); tb[11] = __float2bfloat16(B2.w);
            tb[12] = __float2bfloat16(B3.x); tb[13] = __float2bfloat16(B3.y);
            tb[14] = __float2bfloat16(B3.z); tb[15] = __float2bfloat16(B3.w);
            *(uint4*)(bwr + sc0) = ((const uint4*)tb)[0];
            *(uint4*)(bwr + sc1) = ((const uint4*)tb)[1];
        }
        __syncthreads();                    // tile ready (drains lgkm + vm)

        // ---- T14 prefetch: issue next K-step's loads here so their drain
        // happens at the trailing barrier (window = full MFMA phase).
        if (kt < 7) {
            const int k0 = (kt + 1) * 64;
            const float4* p = (const float4*)(Arow + k0);
            A0 = p[0]; A1 = p[1]; A2 = p[2]; A3 = p[3];
            if (bvalid) {
                const float4* pb = (const float4*)(Brow + k0);
                B0 = pb[0]; B1 = pb[1]; B2 = pb[2]; B3 = pb[3];
            }
        }

        // ---- two K=32 mfma sub-steps over the staged BK=64 tile
        #pragma unroll
        for (int s = 0; s < 2; ++s) {
            const int kb = s * 64 + q * 16;
            bf16x8 af[4], bfr[2];
            #pragma unroll
            for (int i = 0; i < 4; ++i) {
                const int m = wr * 64 + i * 16 + m16;    // m&7 == m16&7
                af[i] = *(const bf16x8*)(lds + m * 128 + (kb ^ swz));
            }
            #pragma unroll
            for (int j = 0; j < 2; ++j) {
                const int nn = wc * 32 + j * 16 + m16;   // nn&7 == m16&7
                bfr[j] = *(const bf16x8*)(lds + 16384 + nn * 128 + (kb ^ swz));
            }
            #pragma unroll
            for (int i = 0; i < 4; ++i)
                #pragma unroll
                for (int j = 0; j < 2; ++j)
                    acc[i][j] = __builtin_amdgcn_mfma_f32_16x16x32_bf16(af[i], bfr[j], acc[i][j], 0, 0, 0);
        }
        __syncthreads();
    }

    // ---- publish per-row stats (quad covers disjoint 128-col segments x 4)
    ssqa += __shfl_xor(ssqa, 1); ssqa += __shfl_xor(ssqa, 2);
    ssqb += __shfl_xor(ssqb, 1); ssqb += __shfl_xor(ssqb, 2);
    if (pseg == 0) {
        ssq_lds[prow] = ssqa;
        msq_lds[prow] = ssqb;
    }
    __syncthreads();

    // ---- epilogue: out = 2*s_r*cross - xsq_r - msq_c
    // C/D layout: col = lane&15, row = quad*4 + reg [verified m89/m91 + R2 pass]
    const float scale = scale_lds;
    const int rowbase = brow * 128 + wr * 64;
    const int colbase = bcol * 128 + wc * 32;
    float msq[2];
    #pragma unroll
    for (int j = 0; j < 2; ++j) {
        msq[j] = msq_lds[wc * 32 + j * 16 + m16];
    }
    #pragma unroll
    for (int i = 0; i < 4; ++i) {
        #pragma unroll
        for (int reg = 0; reg < 4; ++reg) {
            const int lrow = wr * 64 + i * 16 + q * 4 + reg;
            const int row  = rowbase + i * 16 + q * 4 + reg;
            const float nrm = sqrtf(ssq_lds[lrow]);
            const float sc  = scale / (nrm + EPS);       // s_r
            const float sn  = sc * nrm;                  // ||xn||
            const float xsq = sn * sn;
            #pragma unroll
            for (int j = 0; j < 2; ++j) {
                const int col = colbase + j * 16 + m16;
                if (col < C_CLS) {
                    out[(size_t)row * C_CLS + col] = 2.0f * sc * acc[i][j][reg] - xsq - msq[j];
                }
            }
        }
    }
}

// ---- launch ----------------------------------------------------------------
extern "C" void kernel_launch(void* const* d_in, const int* in_sizes, int n_in,
                              void* d_out, int out_size, void* d_ws, size_t ws_size,
                              hipStream_t stream) {
    const float* x     = (const float*)d_in[0];   // [8192][512]
    const float* means = (const float*)d_in[1];   // [1000][512]
    float* out = (float*)d_out;                   // [8192][1000]
    (void)d_ws; (void)ws_size;                    // no workspace needed anymore

    fused_k<<<512, 512, 0, stream>>>(x, means, out);
}

// Round 8
// 89.190 us; speedup vs baseline: 1.0567x; 1.0567x over previous
//
#include <hip/hip_runtime.h>
#include <hip/hip_bf16.h>
#include <stdint.h>

// ---- types -----------------------------------------------------------------
typedef __bf16 bf16x8 __attribute__((ext_vector_type(8)));
typedef float  f32x4  __attribute__((ext_vector_type(4)));
typedef __attribute__((address_space(1))) const void* gptr_t;
typedef __attribute__((address_space(3))) void*       sptr_t;

#define B_ROWS 8192
#define C_CLS  1000
#define C_PAD  1024
#define P_DIM  512
#define EPS    1e-10f

// ---- workspace layout (bytes) ----------------------------------------------
// [0,            1048576)  means_bf16  [1024][512] bf16  (rows >=1000 zeroed)
// [1048576,      1052672)  m_sq        [1024] f32
// [1052672,      9441280)  xn_bf16     [8192][512] bf16
// [9441280,      9474048)  x_sq        [8192] f32
#define WS_MEANS_BF 0
#define WS_MSQ      1048576
#define WS_XN_BF    1052672
#define WS_XSQ      9441280

// ============================================================================
// R8 = restore R5, the measured best (89.13 us). Session ledger:
//   R0 94.4 (64x128, no swz)        R1 89.3 (swz + XCD + BK64)
//   R2 106.1 (fused prep, serial)   R3 92.7 (explicit triple-buf pipeline)
//   R4 93.6 (128^2, 4 waves)        R5 89.1 (128^2, 8 waves)  <- BEST
//   R7 94.3 (full fusion, epilogue scaling: reg-staging+cvt in K-loop
//            critical path loses more than the 17 MB round-trip saves)
// Gradients measured around R5 are all zero/negative: pipelining (R3),
// occupancy trade (R4), fusion either way (R2/R7). Both kernels are below
// the profiler's top-5 cutoff; combined traffic floor ~73 MB ~= 12 us; the
// rest of dur_us is harness-fixed (256 MiB poison fills at ~45 us, 75% peak
// BW). Remaining slack < measured noise -> this is the stopping point.
// ============================================================================

__device__ __forceinline__ float dot8(float4 a, float4 b) {
    return a.x * a.x + a.y * a.y + a.z * a.z + a.w * a.w
         + b.x * b.x + b.y * b.y + b.z * b.z + b.w * b.w;
}

// ---- kernel 1 (fused prep): blocks 0..2047 -> x rows; 2048..2303 -> means ---
__global__ __launch_bounds__(256) void prep_k(const float* __restrict__ x,
                                              const float* __restrict__ means,
                                              __hip_bfloat16* __restrict__ means_bf,
                                              float* __restrict__ m_sq,
                                              __hip_bfloat16* __restrict__ xn_bf,
                                              float* __restrict__ x_sq) {
    const int w = threadIdx.x >> 6;
    const int l = threadIdx.x & 63;
    const int bid = blockIdx.x;

    if (bid < B_ROWS / 4) {
        // ---- x row: one wave per row
        const int row = bid * 4 + w;
        const float4* m0 = (const float4*)means;   // scale source, L2-hot
        float4 ma = m0[l * 2];
        float4 mb = m0[l * 2 + 1];
        float ms = dot8(ma, mb);
        const float4* xr = (const float4*)(x + (size_t)row * P_DIM);
        float4 a = xr[l * 2];
        float4 b = xr[l * 2 + 1];
        float s = dot8(a, b);
        #pragma unroll
        for (int off = 32; off > 0; off >>= 1) {
            ms += __shfl_down(ms, off);
            s  += __shfl_down(s, off);
        }
        ms = __shfl(ms, 0);
        s  = __shfl(s, 0);
        float scale = sqrtf(ms);               // ||means[0]||
        float norm  = sqrtf(s);
        float sc    = scale / (norm + EPS);
        alignas(16) __hip_bfloat16 tmp[8];
        tmp[0] = __float2bfloat16(a.x * sc); tmp[1] = __float2bfloat16(a.y * sc);
        tmp[2] = __float2bfloat16(a.z * sc); tmp[3] = __float2bfloat16(a.w * sc);
        tmp[4] = __float2bfloat16(b.x * sc); tmp[5] = __float2bfloat16(b.y * sc);
        tmp[6] = __float2bfloat16(b.z * sc); tmp[7] = __float2bfloat16(b.w * sc);
        *(uint4*)(xn_bf + (size_t)row * P_DIM + l * 8) = *(const uint4*)tmp;
        if (l == 0) {
            float sn = sc * norm;              // ||xn|| as the reference computes it
            x_sq[row] = sn * sn;
        }
    } else {
        // ---- means row: one wave per class (padded to 1024)
        const int c = (bid - B_ROWS / 4) * 4 + w;
        if (c < C_CLS) {
            const float4* mr = (const float4*)(means + (size_t)c * P_DIM);
            float4 a = mr[l * 2];
            float4 b = mr[l * 2 + 1];
            float s = dot8(a, b);
            alignas(16) __hip_bfloat16 tmp[8];
            tmp[0] = __float2bfloat16(a.x); tmp[1] = __float2bfloat16(a.y);
            tmp[2] = __float2bfloat16(a.z); tmp[3] = __float2bfloat16(a.w);
            tmp[4] = __float2bfloat16(b.x); tmp[5] = __float2bfloat16(b.y);
            tmp[6] = __float2bfloat16(b.z); tmp[7] = __float2bfloat16(b.w);
            *(uint4*)(means_bf + (size_t)c * P_DIM + l * 8) = *(const uint4*)tmp;
            #pragma unroll
            for (int off = 32; off > 0; off >>= 1) s += __shfl_down(s, off);
            if (l == 0) m_sq[c] = s;
        } else {
            uint4 z = {0u, 0u, 0u, 0u};
            *(uint4*)(means_bf + (size_t)c * P_DIM + l * 8) = z;
            if (l == 0) m_sq[c] = 0.0f;
        }
    }
}

// ---- kernel 2: logits = 2*(xn @ means^T) - x_sq - m_sq ---------------------
// 128x128 tile, 8 waves (2 blocks/CU x 8 waves = 16 waves/CU), 2-barrier
// schedule, global_load_lds staging, XOR swizzle (T2), XCD remap (T1).
// Wave (wr=w>>2, wc=w&3) owns a 64x32 sub-tile: acc[4][2].
// Grid 512 = 64 brow x 8 bcol = exactly 2 blocks/CU, one pass.
// LDS 32 KB: A[128][128B] @0, B[128][128B] @16384.
// Swizzle bank check (ds_read): chunk = (s*4+q)^(m16&7) -> 8 lanes per chunk
// slot = conflict-free b128 minimum.
__global__ __launch_bounds__(512, 4) void gemm_k(const __hip_bfloat16* __restrict__ A,   // xn   [8192][512]
                                                 const __hip_bfloat16* __restrict__ B,   // means[1024][512]
                                                 const float* __restrict__ x_sq,
                                                 const float* __restrict__ m_sq,
                                                 float* __restrict__ out) {
    __shared__ alignas(16) char lds[32768];
    const int t   = threadIdx.x;
    const int w   = t >> 6;         // wave 0..7
    const int l   = t & 63;
    const int q   = l >> 4;         // quad 0..3
    const int m16 = l & 15;
    const int wr  = w >> 2;         // wave row 0..1 (64-row halves)
    const int wc  = w & 3;          // wave col 0..3 (32-col quarters)

    // XCD-aware remap: n%8 = XCD; each XCD owns 8 consecutive brows x all bcols.
    const int n_blk  = blockIdx.x;            // 0..511
    const int xcd    = n_blk & 7;
    const int within = n_blk >> 3;            // 0..63
    const int brow   = xcd * 8 + (within & 7);     // 0..63 (128-row tiles)
    const int bcol   = within >> 3;                // 0..7  (128-col tiles)

    f32x4 acc[4][2];
    #pragma unroll
    for (int i = 0; i < 4; ++i)
        #pragma unroll
        for (int j = 0; j < 2; ++j) {
            f32x4 z = {0.f, 0.f, 0.f, 0.f};
            acc[i][j] = z;
        }

    const char* Abase = (const char*)A + (size_t)(brow * 128) * (P_DIM * 2);
    const char* Bbase = (const char*)B + (size_t)(bcol * 128) * (P_DIM * 2);

    const int swz = (m16 & 7) << 4;     // read-side XOR, uniform across frags

    for (int k0 = 0; k0 < P_DIM; k0 += 64) {
        // ---- stage 32 KB in 4 rounds of 8 KB (512 threads x 16 B):
        // rounds 0-1 -> A region, 2-3 -> B region. LDS dest is wave-uniform
        // base + lane*16 (linear); global source is inverse-swizzled
        // (chunk c of row holds global chunk c^(row&7)).
        #pragma unroll
        for (int r = 0; r < 4; ++r) {
            const int o   = (r & 1) * 8192 + w * 1024 + l * 16;   // 0..16384 in region
            const int row = o >> 7;                               // 0..127
            const int c   = (o >> 4) & 7;
            const char* gb = (r < 2) ? Abase : Bbase;
            const char* g  = gb + (size_t)row * (P_DIM * 2) + k0 * 2 + ((c ^ (row & 7)) << 4);
            char* dst = lds + ((r < 2) ? 0 : 16384) + (r & 1) * 8192 + w * 1024;
            __builtin_amdgcn_global_load_lds((gptr_t)g, (sptr_t)dst, 16, 0, 0);
        }
        __syncthreads();

        // ---- two K=32 mfma sub-steps over the staged BK=64 tile
        #pragma unroll
        for (int s = 0; s < 2; ++s) {
            const int kb = s * 64 + q * 16;      // byte offset within 128-B row
            bf16x8 af[4], bfr[2];
            #pragma unroll
            for (int i = 0; i < 4; ++i) {
                const int m = wr * 64 + i * 16 + m16;    // m&7 == m16&7
                af[i] = *(const bf16x8*)(lds + m * 128 + (kb ^ swz));
            }
            #pragma unroll
            for (int j = 0; j < 2; ++j) {
                const int nn = wc * 32 + j * 16 + m16;   // nn&7 == m16&7
                bfr[j] = *(const bf16x8*)(lds + 16384 + nn * 128 + (kb ^ swz));
            }
            #pragma unroll
            for (int i = 0; i < 4; ++i)
                #pragma unroll
                for (int j = 0; j < 2; ++j)
                    acc[i][j] = __builtin_amdgcn_mfma_f32_16x16x32_bf16(af[i], bfr[j], acc[i][j], 0, 0, 0);
        }
        __syncthreads();
    }

    // ---- epilogue: out = 2*cross - x_sq[row] - m_sq[col]
    // C/D layout: col = lane&15, row = quad*4 + reg [verified m89/m91 + R2 pass]
    const int rowbase = brow * 128 + wr * 64;
    const int colbase = bcol * 128 + wc * 32;
    float msq[2];
    #pragma unroll
    for (int j = 0; j < 2; ++j) {
        const int col = colbase + j * 16 + m16;
        msq[j] = (col < C_CLS) ? m_sq[col] : 0.0f;
    }
    #pragma unroll
    for (int i = 0; i < 4; ++i) {
        #pragma unroll
        for (int reg = 0; reg < 4; ++reg) {
            const int row = rowbase + i * 16 + q * 4 + reg;
            const float xsq = x_sq[row];
            #pragma unroll
            for (int j = 0; j < 2; ++j) {
                const int col = colbase + j * 16 + m16;
                if (col < C_CLS) {
                    out[(size_t)row * C_CLS + col] = 2.0f * acc[i][j][reg] - xsq - msq[j];
                }
            }
        }
    }
}

// ---- launch ----------------------------------------------------------------
extern "C" void kernel_launch(void* const* d_in, const int* in_sizes, int n_in,
                              void* d_out, int out_size, void* d_ws, size_t ws_size,
                              hipStream_t stream) {
    const float* x     = (const float*)d_in[0];   // [8192][512]
    const float* means = (const float*)d_in[1];   // [1000][512]
    float* out = (float*)d_out;                   // [8192][1000]
    char* ws = (char*)d_ws;

    __hip_bfloat16* means_bf = (__hip_bfloat16*)(ws + WS_MEANS_BF);
    float*          m_sq     = (float*)(ws + WS_MSQ);
    __hip_bfloat16* xn_bf    = (__hip_bfloat16*)(ws + WS_XN_BF);
    float*          x_sq     = (float*)(ws + WS_XSQ);

    prep_k<<<B_ROWS / 4 + C_PAD / 4, 256, 0, stream>>>(x, means, means_bf, m_sq, xn_bf, x_sq);
    gemm_k<<<512, 512, 0, stream>>>(xn_bf, means_bf, x_sq, m_sq, out);
}